// Round 6
// baseline (44.900 us; speedup 1.0000x reference)
//
#include <hip/hip_runtime.h>

// GAE: A_t = delta_t + (gamma*lam)*A_{t+1} backward over S=4096; returns = A + values.
// Exact parallel weighted suffix scan, all-register, wave-coalesced float4 I/O,
// nontemporal stores. R5: 4 rows per block with a 2-deep software pipeline
// (issue next row's loads before computing current row) + double-buffered Tlds
// so each row costs one barrier. Goal: overlap next-row reads with current-row
// compute+stores for a steadier HBM read/write mix (R4 est. only ~72% HBM util).

#define GAMMA 0.99f
#define LAM   0.95f

typedef float fvec4 __attribute__((ext_vector_type(4)));

constexpr int S_LEN = 4096;
constexpr int TPB   = 256;
constexpr int NSEG  = 4;   // segments of 1024 = TPB*4 elements
constexpr int ROWS  = 4;   // rows per block

__global__ __launch_bounds__(TPB) void gae_kernel(const float* __restrict__ rewards,
                                                  const float* __restrict__ values,
                                                  const float* __restrict__ next_values,
                                                  float* __restrict__ out, int B) {
    __shared__ float Tlds[2][16];

    const int tid  = threadIdx.x;
    const int lane = tid & 63;
    const int w    = tid >> 6;
    const float c  = GAMMA * LAM;
    const float q4 = c * c * c * c;

    float qs[6];                    // q4^(2^k)
    {
        float qd = q4;
#pragma unroll
        for (int k = 0; k < 6; ++k) { qs[k] = qd; qd *= qd; }
    }
    const float Q256 = qs[5] * qs[5];   // c^256
    float qp = 1.f;                     // q4^(63-lane)
    {
        int e = 63 - lane;
#pragma unroll
        for (int k = 0; k < 6; ++k) if ((e >> k) & 1) qp *= qs[k];
    }
    const float c2 = c * c, c3 = c2 * c;

    const int b0 = blockIdx.x * ROWS;

    auto LOAD = [&](int b, fvec4 (&v4)[NSEG], fvec4 (&r4)[NSEG], float (&vn)[NSEG]) {
        const float* vrow = values  + (size_t)b * S_LEN;
        const float* rrow = rewards + (size_t)b * S_LEN;
#pragma unroll
        for (int s = 0; s < NSEG; ++s) {
            const int g0 = s * 1024 + 4 * tid;
            v4[s] = *(const fvec4*)(vrow + g0);
            r4[s] = *(const fvec4*)(rrow + g0);
        }
#pragma unroll
        for (int s = 0; s < NSEG; ++s) {
            const int g4 = s * 1024 + 4 * tid + 4;
            if (s == NSEG - 1 && tid == TPB - 1) vn[s] = next_values[b];
            else                                 vn[s] = vrow[g4];
        }
    };

    auto COMPUTE = [&](int b, int par, fvec4 (&v4)[NSEG], fvec4 (&r4)[NSEG],
                       float (&vn)[NSEG]) {
        float a0[NSEG], a1[NSEG], a2[NSEG], a3[NSEG], Wn[NSEG];
        float Tk = 0.f;
#pragma unroll
        for (int s = 0; s < NSEG; ++s) {
            float d3 = fmaf(GAMMA, vn[s],   r4[s].w) - v4[s].w;
            float d2 = fmaf(GAMMA, v4[s].w, r4[s].z) - v4[s].z;
            float d1 = fmaf(GAMMA, v4[s].z, r4[s].y) - v4[s].y;
            float d0 = fmaf(GAMMA, v4[s].y, r4[s].x) - v4[s].x;
            float t3 = d3;
            float t2 = fmaf(c, t3, d2);
            float t1 = fmaf(c, t2, d1);
            float t0 = fmaf(c, t1, d0);
            a3[s] = t3; a2[s] = t2; a1[s] = t1; a0[s] = t0;

            float x = t0;   // intra-wave weighted suffix scan, factor q4
#pragma unroll
            for (int dlog = 0; dlog < 6; ++dlog) {
                int d = 1 << dlog;
                float other = __shfl_down(x, d);
                if (lane + d < 64) x = fmaf(qs[dlog], other, x);
            }
            Wn[s] = __shfl_down(x, 1);
            float tb = __shfl(x, 0);        // chunk total T_{m=s*4+w}
            if (lane == s) Tk = tb;
        }

        // cross-chunk combine: 16 totals, factor c^256, redundant per-wave scan
        if (lane < NSEG) Tlds[par][lane * 4 + w] = Tk;
        __syncthreads();
        float tv = (lane < 16) ? Tlds[par][lane] : 0.f;
        {
            float Qd = Q256;
#pragma unroll
            for (int dlog = 0; dlog < 4; ++dlog) {
                int d = 1 << dlog;
                float other = __shfl_down(tv, d);
                if (lane + d < 16) tv = fmaf(Qd, other, tv);
                Qd *= Qd;
            }
        }

        float* adv_row = out + (size_t)b * S_LEN;
        float* ret_row = out + (size_t)B * S_LEN + (size_t)b * S_LEN;
#pragma unroll
        for (int s = 0; s < NSEG; ++s) {
            const int m = s * 4 + w;
            float Cm = (m == 15) ? 0.f : __shfl(tv, m + 1);     // carry into chunk m
            float ct = (lane == 63) ? Cm : fmaf(qp, Cm, Wn[s]); // carry into thread
            float o3 = fmaf(c,  ct, a3[s]);
            float o2 = fmaf(c2, ct, a2[s]);
            float o1 = fmaf(c3, ct, a1[s]);
            float o0 = fmaf(q4, ct, a0[s]);
            const int g0 = s * 1024 + 4 * tid;
            fvec4 av; av.x = o0; av.y = o1; av.z = o2; av.w = o3;
            fvec4 rv = av + v4[s];
            __builtin_nontemporal_store(av, (fvec4*)(adv_row + g0));
            __builtin_nontemporal_store(rv, (fvec4*)(ret_row + g0));
        }
    };

    fvec4 vA[NSEG], rA[NSEG], vB[NSEG], rB[NSEG];
    float vnA[NSEG], vnB[NSEG];

    LOAD(b0 + 0, vA, rA, vnA);
    LOAD(b0 + 1, vB, rB, vnB);          // in flight during row 0 compute
    COMPUTE(b0 + 0, 0, vA, rA, vnA);
    LOAD(b0 + 2, vA, rA, vnA);          // in flight during row 1 compute
    COMPUTE(b0 + 1, 1, vB, rB, vnB);
    LOAD(b0 + 3, vB, rB, vnB);          // in flight during row 2 compute
    COMPUTE(b0 + 2, 0, vA, rA, vnA);
    COMPUTE(b0 + 3, 1, vB, rB, vnB);
}

extern "C" void kernel_launch(void* const* d_in, const int* in_sizes, int n_in,
                              void* d_out, int out_size, void* d_ws, size_t ws_size,
                              hipStream_t stream) {
    const float* rewards     = (const float*)d_in[0];
    const float* values      = (const float*)d_in[1];
    const float* next_values = (const float*)d_in[2];
    float* out = (float*)d_out;
    const int B = in_sizes[2];   // 4096
    gae_kernel<<<B / ROWS, TPB, 0, stream>>>(rewards, values, next_values, out, B);
}

// Round 7
// 44.127 us; speedup vs baseline: 1.0175x; 1.0175x over previous
//
#include <hip/hip_runtime.h>

// GAE: A_t = delta_t + (gamma*lam)*A_{t+1} backward over S=4096; returns = A + values.
// FINAL (R4 revert — best measured, 43.9us): exact parallel weighted suffix scan,
// all-register, fully wave-coalesced float4 I/O, nontemporal stores.
// Decomposition: row = 4 segments x 1024; thread owns one float4 per segment
// (per-instruction the wave covers contiguous 1024B). 16 chunk totals (256 elts
// each) combined by a redundant per-wave 16-entry shuffle scan; 1 barrier total.
// 268MB logical / 43.9us = 6.1 TB/s = 97% of measured copy ceiling (6.29 TB/s).
// R5's cross-row software pipeline was neutral -> TLP already saturates HBM.

#define GAMMA 0.99f
#define LAM   0.95f

typedef float fvec4 __attribute__((ext_vector_type(4)));

constexpr int S_LEN = 4096;
constexpr int TPB   = 256;
constexpr int NSEG  = 4;      // segments of 1024 = TPB*4

__global__ __launch_bounds__(TPB) void gae_kernel(const float* __restrict__ rewards,
                                                  const float* __restrict__ values,
                                                  const float* __restrict__ next_values,
                                                  float* __restrict__ out, int B) {
    __shared__ float Tlds[16];

    const int b    = blockIdx.x;
    const int tid  = threadIdx.x;
    const int lane = tid & 63;
    const int w    = tid >> 6;
    const float c  = GAMMA * LAM;
    const float q4 = c * c * c * c;

    const float* vrow = values  + (size_t)b * S_LEN;
    const float* rrow = rewards + (size_t)b * S_LEN;
    const float  nv   = next_values[b];

    // ---- load all segments: wave-contiguous float4 (1024B per instruction) ----
    fvec4 v4[NSEG], r4[NSEG];
    float vn[NSEG];
#pragma unroll
    for (int s = 0; s < NSEG; ++s) {
        const int g0 = s * 1024 + 4 * tid;
        v4[s] = *(const fvec4*)(vrow + g0);
        r4[s] = *(const fvec4*)(rrow + g0);
    }
#pragma unroll
    for (int s = 0; s < NSEG; ++s) {
        const int g4 = s * 1024 + 4 * tid + 4;
        if (s == NSEG - 1 && tid == TPB - 1) vn[s] = nv;       // bootstrap
        else                                 vn[s] = vrow[g4]; // cache-hot neighbor
    }

    // ---- per segment: local 4-elt backward scan + 64-lane weighted suffix scan ----
    float a0[NSEG], a1[NSEG], a2[NSEG], a3[NSEG]; // local suffix values (zero carry)
    float Wn[NSEG];                               // x(lane+1) within wave
    float Tk = 0.f;                               // chunk total held by lane s
    float qs[6];                                  // q4^(2^k), same every segment
    {
        float qd = q4;
#pragma unroll
        for (int k = 0; k < 6; ++k) { qs[k] = qd; qd *= qd; }
    }
    const float Q256 = qs[5] * qs[5]; // c^256

#pragma unroll
    for (int s = 0; s < NSEG; ++s) {
        // deltas
        float d3 = fmaf(GAMMA, vn[s],    r4[s].w) - v4[s].w;
        float d2 = fmaf(GAMMA, v4[s].w,  r4[s].z) - v4[s].z;
        float d1 = fmaf(GAMMA, v4[s].z,  r4[s].y) - v4[s].y;
        float d0 = fmaf(GAMMA, v4[s].y,  r4[s].x) - v4[s].x;
        // local backward scan
        float t3 = d3;
        float t2 = fmaf(c, t3, d2);
        float t1 = fmaf(c, t2, d1);
        float t0 = fmaf(c, t1, d0);
        a3[s] = t3; a2[s] = t2; a1[s] = t1; a0[s] = t0;

        // intra-wave weighted suffix scan, factor q4
        float x = t0;
#pragma unroll
        for (int dlog = 0; dlog < 6; ++dlog) {
            int d = 1 << dlog;
            float other = __shfl_down(x, d);
            if (lane + d < 64) x = fmaf(qs[dlog], other, x);
        }
        Wn[s] = __shfl_down(x, 1);        // x(lane+1); garbage at lane 63 (unused)
        float tb = __shfl(x, 0);          // chunk total T_{m = s*4+w}
        if (lane == s) Tk = tb;
    }

    // ---- cross-chunk combine: 16 totals, factor c^256, redundant per-wave scan ----
    if (lane < NSEG) Tlds[lane * 4 + w] = Tk;
    __syncthreads();
    float tv = (lane < 16) ? Tlds[lane] : 0.f;
    {
        float Qd = Q256;
#pragma unroll
        for (int dlog = 0; dlog < 4; ++dlog) {
            int d = 1 << dlog;
            float other = __shfl_down(tv, d);
            if (lane + d < 16) tv = fmaf(Qd, other, tv);
            Qd *= Qd;
        }
    }
    // tv(lane=m) = S_m = suffix of chunk totals from chunk m

    // q4^(63-lane) for the wave-carry weight (binary exponentiation)
    float qp = 1.f;
    {
        int e = 63 - lane;
#pragma unroll
        for (int k = 0; k < 6; ++k) if ((e >> k) & 1) qp *= qs[k];
    }

    // ---- apply carries, store (coalesced nontemporal float4) ----
    float* adv_row = out + (size_t)b * S_LEN;
    float* ret_row = out + (size_t)B * S_LEN + (size_t)b * S_LEN;
    const float c2 = c * c, c3 = c2 * c;
#pragma unroll
    for (int s = 0; s < NSEG; ++s) {
        const int m = s * 4 + w;
        float Cm = (m == 15) ? 0.f : __shfl(tv, m + 1);        // carry into chunk m
        float ct = (lane == 63) ? Cm : fmaf(qp, Cm, Wn[s]);    // carry into thread
        float o3 = fmaf(c,  ct, a3[s]);
        float o2 = fmaf(c2, ct, a2[s]);
        float o1 = fmaf(c3, ct, a1[s]);
        float o0 = fmaf(q4, ct, a0[s]);
        const int g0 = s * 1024 + 4 * tid;
        fvec4 av; av.x = o0; av.y = o1; av.z = o2; av.w = o3;
        fvec4 rv = av + v4[s];
        __builtin_nontemporal_store(av, (fvec4*)(adv_row + g0));
        __builtin_nontemporal_store(rv, (fvec4*)(ret_row + g0));
    }
}

extern "C" void kernel_launch(void* const* d_in, const int* in_sizes, int n_in,
                              void* d_out, int out_size, void* d_ws, size_t ws_size,
                              hipStream_t stream) {
    const float* rewards     = (const float*)d_in[0];
    const float* values      = (const float*)d_in[1];
    const float* next_values = (const float*)d_in[2];
    float* out = (float*)d_out;
    const int B = in_sizes[2];   // 4096
    gae_kernel<<<B, TPB, 0, stream>>>(rewards, values, next_values, out, B);
}